// Round 14
// baseline (173.120 us; speedup 1.0000x reference)
//
#include <hip/hip_runtime.h>
#include <math.h>

#define BB 16
#define PP (768*768)        // 589824
#define NBINS 1024
#define CHUNKS 144          // blocks per image; pixels/block = 4096 exactly (no tail)
#define PIXB (PP / CHUNKS)  // 4096
#define PC4  (PIXB / 4)     // 1024 float4 per chunk = 4 * 256
#define KALL 176947         // int(P * 0.3)

#define LOV_LO (-17.0f)
#define LOV_RANGE 34.0f

typedef unsigned long long u64;

struct AccR { float lov_i, ft_i, ohem_i; unsigned posb; };                  // 16 B

__device__ inline float wred_sum(float v) {
  #pragma unroll
  for (int o = 32; o > 0; o >>= 1) v += __shfl_down(v, o, 64);
  return v;
}
__device__ inline float wred_max(float v) {
  #pragma unroll
  for (int o = 32; o > 0; o >>= 1) v = fmaxf(v, __shfl_down(v, o, 64));
  return v;
}

// ---------------- K1: histogram-only fused pass; 12 loads pinned in flight ----------------
// hist1[bin] = count | pos<<16
// hist3[bin] = #(t==0 && m!=1) | #(t==1 && m!=1)<<16   (atomic fires only when m!=1)
__global__ __launch_bounds__(256, 6) void k_main(const float* __restrict__ logits,
                                                 const int* __restrict__ targets,
                                                 const float* __restrict__ mask,
                                                 float* __restrict__ bce0g,
                                                 unsigned* __restrict__ partial1,
                                                 unsigned* __restrict__ partial3,
                                                 unsigned* __restrict__ flags,
                                                 unsigned* __restrict__ tickets)
{
  const int b = blockIdx.y;
  const int chunk = blockIdx.x;
  __shared__ unsigned hist1[NBINS];        // 4 KB
  __shared__ unsigned hist3[NBINS];        // 4 KB
  __shared__ unsigned s_any3;
  {  // uint4 zero-init: exactly one store per thread per array
    uint4 z; z.x = z.y = z.z = z.w = 0u;
    ((uint4*)hist1)[threadIdx.x] = z;
    ((uint4*)hist3)[threadIdx.x] = z;
  }
  if (threadIdx.x == 0) s_any3 = 0u;
  // zero tickets for k_tail (kernel-boundary ordering makes this safe)
  if (b == 0 && chunk == 0 && threadIdx.x < 32) tickets[threadIdx.x] = 0u;
  __syncthreads();

  const float4* l4 = (const float4*)(logits + (size_t)b * PP);
  const int4*   t4 = (const int4*)(targets + (size_t)b * PP);
  const float4* m4 = (const float4*)(mask + (size_t)b * PP);

  const float lov_scale = (float)NBINS / LOV_RANGE;

  // exact fallback loss_i[0]
  if (chunk == 0 && threadIdx.x == 0) {
    float l = logits[(size_t)b * PP];
    float tf = (float)targets[(size_t)b * PP];
    float m = mask[(size_t)b * PP];
    float ex = __expf(-fabsf(l));
    bce0g[b] = (fmaxf(l, 0.f) + __logf(1.f + ex) - l * tf) * m;
  }

  const int base4 = chunk * PC4;

  // ---- issue ALL 12 dwordx4 loads back-to-back ----
  float4 L[4]; int4 T[4]; float4 M[4];
  #pragma unroll
  for (int it = 0; it < 4; ++it) {
    int i = base4 + it * 256 + threadIdx.x;
    L[it] = l4[i]; T[it] = t4[i]; M[it] = m4[i];
  }
  // register tether: asm reads one component of each dwordx4 result so the
  // loads cannot be sunk below this point; one bulk s_waitcnt here.
  asm volatile("" ::
      "v"(L[0].x), "v"(L[1].x), "v"(L[2].x), "v"(L[3].x),
      "v"(T[0].x), "v"(T[1].x), "v"(T[2].x), "v"(T[3].x),
      "v"(M[0].x), "v"(M[1].x), "v"(M[2].x), "v"(M[3].x));

  unsigned bad = 0u;
  auto px = [&](float l, int ti, float m) {
    float s = fmaf(2.f, (float)ti, -1.f);
    float e = fmaf(-l, s, 1.f);                      // lovasz error
    int bin = (int)((e - LOV_LO) * lov_scale);
    bin = bin < 0 ? 0 : (bin > NBINS - 1 ? NBINS - 1 : bin);
    atomicAdd(&hist1[bin], 1u | ((unsigned)ti << 16));
    if (m != 1.0f) {                                 // never fires when mask==1
      bad = 1u;
      atomicAdd(&hist3[bin], ti ? 0x10000u : 1u);
    }
  };

  #pragma unroll
  for (int it = 0; it < 4; ++it) {
    px(L[it].x, T[it].x, M[it].x); px(L[it].y, T[it].y, M[it].y);
    px(L[it].z, T[it].z, M[it].z); px(L[it].w, T[it].w, M[it].w);
  }

  if (bad) s_any3 = 1u;     // benign race: all writers store 1
  __syncthreads();
  const unsigned any3 = s_any3;
  if (threadIdx.x == 0) flags[(size_t)b * CHUNKS + chunk] = any3;

  // non-atomic coalesced uint4 flush: one dwordx4 store per thread
  {
    uint4* d1 = (uint4*)(partial1 + ((size_t)b * CHUNKS + chunk) * NBINS);
    d1[threadIdx.x] = ((const uint4*)hist1)[threadIdx.x];
    if (any3) {
      uint4* d3 = (uint4*)(partial3 + ((size_t)b * CHUNKS + chunk) * NBINS);
      d3[threadIdx.x] = ((const uint4*)hist3)[threadIdx.x];
    }
  }
}

// ---------------- K2 (k_tail): branch-free slice reduce -> elected per-image scan -> combine ----------------
__global__ __launch_bounds__(256) void k_tail(const unsigned* __restrict__ partial1,
                                              const unsigned* __restrict__ partial3,
                                              const unsigned* __restrict__ flags,
                                              uint4* __restrict__ ghist,
                                              const float* __restrict__ bce0g,
                                              AccR* __restrict__ acc,
                                              unsigned* __restrict__ tickets,
                                              float* __restrict__ out)
{
  const int img = blockIdx.y;          // 16
  const int slice = blockIdx.x;        // NBINS/64 = 16 slices x 64 bins
  const int t = threadIdx.x;
  __shared__ unsigned sA[256], sB[256], sCc[256];
  __shared__ float sf[256], sg[256];
  __shared__ float wsum[4][6];
  __shared__ unsigned short s_list[CHUNKS];
  __shared__ int s_n;
  __shared__ unsigned s_do;
  __shared__ unsigned p_sh, ng_total_sh;
  __shared__ float pos_sh, tp_sh, spr_sh, mx_sh, npos_shf, nm0_shf;

  // ---- phase 1: branch-free reduce of this slice's 64 bins across 144 partials ----
  {
    const int lane = t & 63, g = t >> 6;           // 4 groups x 36 partials
    const int bin = slice * 64 + lane;
    const unsigned* s1 = partial1 + ((size_t)img * CHUNKS + (size_t)g * 36) * NBINS + bin;
    unsigned c = 0, q = 0;
    #pragma unroll 6
    for (int p = 0; p < 36; ++p) {
      unsigned v = s1[(size_t)p * NBINS];
      c += v & 0xFFFFu; q += v >> 16;
    }
    sA[t] = c; sB[t] = q;

    if (t == 0) {   // compact flagged-chunk list (empty when mask==1 everywhere)
      int n = 0;
      for (int p = 0; p < CHUNKS; ++p) if (flags[(size_t)img * CHUNKS + p]) s_list[n++] = (unsigned short)p;
      s_n = n;
    }
    __syncthreads();

    if (t < 64) {
      unsigned ct = sA[t] + sA[64 + t] + sA[128 + t] + sA[192 + t];
      unsigned qt = sB[t] + sB[64 + t] + sB[128 + t] + sB[192 + t];
      const int bn = slice * 64 + t;
      unsigned a = 0, b2 = 0;
      for (int k = 0; k < s_n; ++k) {
        int p = s_list[k];
        unsigned v = partial3[((size_t)img * CHUNKS + p) * NBINS + bn];
        a += v & 0xFFFFu; b2 += v >> 16;
      }
      uint4 o; o.x = ct; o.y = qt; o.z = a; o.w = b2;
      ghist[(size_t)img * NBINS + bn] = o;
    }
  }

  // ---- publish + elect: last slice-block of this image runs the scan ----
  __threadfence();
  __syncthreads();
  if (t == 0) {
    unsigned ret = atomicAdd(&tickets[img], 1u);
    s_do = (ret == (unsigned)(NBINS / 64) - 1) ? 1u : 0u;
  }
  __syncthreads();
  if (!s_do) return;
  __threadfence();   // acquire other slices' ghist writes

  // ---- phase 2: reconstruct sums + descending walk (R13 k_scan body) ----
  const float lov_d = LOV_RANGE / (float)NBINS;
  const uint4* gh = ghist + (size_t)img * NBINS;
  const int CH = NBINS / 256;          // 4 bins per thread

  uint4 loc[4];
  unsigned tc = 0, tq = 0, tn = 0;
  float pos_s = 0.f, tp_s = 0.f, spr_s = 0.f, mx_s = 0.f, npos_s = 0.f, nm0_s = 0.f;
  #pragma unroll
  for (int k = 0; k < 4; ++k) {
    int j = NBINS - 1 - (t * CH + k);
    uint4 v = gh[j]; loc[k] = v;
    unsigned c = v.x, q = v.y, a = v.z, b2 = v.w;
    tc += c; tq += q;
    unsigned ng = (c - q) - a;         // tissue negatives in bin
    tn += ng;
    npos_s += (float)(q - b2);         // tissue positives (exact integers)
    nm0_s  += (float)(a + b2);         // pixels with m != 1
    if (c) {
      float e = LOV_LO + ((float)j + 0.5f) * lov_d;
      float l1 = 1.f - e;              // logit for positives; negatives have l = -l1
      float ex = __expf(-fabsf(l1));
      float bceB = fmaxf(-l1, 0.f) + __logf(1.f + ex);   // softplus(e-1): loss for BOTH classes
      float sig1 = ((l1 >= 0.f) ? 1.f : ex) * __builtin_amdgcn_rcpf(1.f + ex);  // sigmoid(l1)
      unsigned qt = q - b2;
      pos_s = fmaf((float)qt, bceB, pos_s);
      tp_s  = fmaf((float)q, sig1, tp_s);
      spr_s = fmaf((float)q, sig1, spr_s);
      spr_s = fmaf((float)(c - q), 1.f - sig1, spr_s);
      if (qt + ng > 0) mx_s = fmaxf(mx_s, bceB);
    }
  }
  {
    float v0 = wred_sum(pos_s), v1 = wred_sum(tp_s), v2 = wred_sum(spr_s);
    float v3 = wred_max(mx_s), v4 = wred_sum(npos_s), v5 = wred_sum(nm0_s);
    int w = t >> 6, lane = t & 63;
    if (lane == 0) {
      wsum[w][0] = v0; wsum[w][1] = v1; wsum[w][2] = v2;
      wsum[w][3] = v3; wsum[w][4] = v4; wsum[w][5] = v5;
    }
  }
  sA[t] = tc; sB[t] = tq; sCc[t] = tn;
  __syncthreads();
  if (t == 0) {
    pos_sh = wsum[0][0] + wsum[1][0] + wsum[2][0] + wsum[3][0];
    tp_sh  = wsum[0][1] + wsum[1][1] + wsum[2][1] + wsum[3][1];
    spr_sh = wsum[0][2] + wsum[1][2] + wsum[2][2] + wsum[3][2];
    mx_sh  = fmaxf(fmaxf(wsum[0][3], wsum[1][3]), fmaxf(wsum[2][3], wsum[3][3]));
    npos_shf = wsum[0][4] + wsum[1][4] + wsum[2][4] + wsum[3][4];
    nm0_shf  = wsum[0][5] + wsum[1][5] + wsum[2][5] + wsum[3][5];
    unsigned aI = 0, aC = 0, aN = 0;
    for (int i = 0; i < 256; i++) {
      unsigned ci = sA[i], qi = sB[i], ni = sCc[i];
      sA[i] = aI; sB[i] = aC; sCc[i] = aN;
      aI += ci; aC += qi; aN += ni;
    }
    p_sh = aC; ng_total_sh = aN;
  }
  __syncthreads();

  const unsigned sum_t = p_sh;                 // total positives (unmasked), exact
  const float p = (float)sum_t;
  const bool has_pos = sum_t > 0;
  const unsigned n_neg_total = (unsigned)PP - sum_t;
  int n_pos = (int)npos_shf;                   // tissue positives, exact
  int n_remain = KALL - n_pos; if (n_remain < 0) n_remain = 0;

  float lov_local = 0.f, ns_local = 0.f;
  {
    unsigned I = sA[t], C = sB[t], NG = sCc[t];
    float Jprev = has_pos ? (1.f - (p - (float)C) / (p + (float)I - (float)C)) : 0.f;
    #pragma unroll
    for (int k = 0; k < 4; ++k) {
      int j = NBINS - 1 - (t * CH + k);
      uint4 v = loc[k];
      unsigned c = v.x;
      if (c) {
        unsigned q = v.y;
        unsigned ng = (c - q) - v.z;
        float e = LOV_LO + ((float)j + 0.5f) * lov_d;
        if (has_pos) {
          float re = fmaxf(e, 0.f);
          if (n_neg_total > 0) {
            I += c; C += q;
            float Jb = 1.f - (p - (float)C) / (p + (float)I - (float)C);
            lov_local += re * (Jb - Jprev);
            Jprev = Jb;
          } else {
            double hi = (double)I + (double)c;
            double s = (hi * (hi + 1.0) - (double)I * ((double)I + 1.0)) * 0.5 / (double)p;
            lov_local += re * (float)s;
            I += c;
          }
        }
        if (n_remain > 0 && ng) {
          long long rem = (long long)n_remain - (long long)NG;
          unsigned take = rem <= 0 ? 0u : (rem >= (long long)ng ? ng : (unsigned)rem);
          if (take) {
            float l = e - 1.f;                         // negatives: e = 1 + l
            float nloss = fmaxf(l, 0.f) + __logf(1.f + __expf(-fabsf(l)));
            ns_local += (float)take * nloss;
          }
          NG += ng;
        }
      }
    }
  }
  sf[t] = lov_local; sg[t] = ns_local; __syncthreads();
  for (int off = 128; off > 0; off >>= 1) {
    if (t < off) { sf[t] += sf[t + off]; sg[t] += sg[t + off]; }
    __syncthreads();
  }

  if (t == 0) {
    float lov = sf[0];
    float neg_sum = sg[0];
    unsigned kept = (n_remain > 0)
        ? ((unsigned)n_remain < ng_total_sh ? (unsigned)n_remain : ng_total_sh) : 0u;
    float cnt = (float)n_pos + (float)kept;
    float ohem;
    if (cnt > 0.f) ohem = (pos_sh + neg_sum) / cnt;
    else ohem = ((float)PP - nm0_shf > 0.f) ? mx_sh : bce0g[img];
    float tp = tp_sh;
    float fn = p - tp;
    float fp = spr_sh - tp;
    float tv = (tp + 1e-6f) / (tp + 0.3f * fn + 0.7f * fp + 1e-6f);
    float ft = powf(fmaxf(1.f - tv, 0.f), 1.33f);
    acc[img].lov_i = lov; acc[img].ft_i = ft; acc[img].ohem_i = ohem;
    acc[img].posb = has_pos ? 1u : 0u;

    __threadfence();
    unsigned ret = atomicAdd(&tickets[16], 1u);
    if (ret == BB - 1) {                 // last image: final combine
      __threadfence();
      volatile AccR* va = acc;
      float os = 0.f, fts = 0.f, lvs = 0.f; int np = 0;
      for (int i = 0; i < BB; i++) {
        os += va[i].ohem_i;
        if (va[i].posb) { np++; fts += va[i].ft_i; lvs += va[i].lov_i; }
      }
      float denom = (np > 0) ? (float)np : 1.f;
      float r = os / (float)BB;
      if (np > 0) r += fts / denom + 0.2f * (lvs / denom);
      out[0] = r;
    }
  }
}

extern "C" void kernel_launch(void* const* d_in, const int* in_sizes, int n_in,
                              void* d_out, int out_size, void* d_ws, size_t ws_size,
                              hipStream_t stream) {
  const float* logits  = (const float*)d_in[0];
  const int*   targets = (const int*)d_in[1];
  const float* mask    = (const float*)d_in[2];
  float* out = (float*)d_out;

  char* ws = (char*)d_ws;
  AccR*     acc      = (AccR*)ws;                        // 256 B
  unsigned* tickets  = (unsigned*)(ws + 256);            // 32 u32
  float*    bce0g    = (float*)(ws + 512);               // 64 B
  unsigned* flags    = (unsigned*)(ws + 4096);           // 16*144*4 = 9.2 KB
  uint4*    ghist    = (uint4*)(ws + (64 << 10));        // 16*1024*16 = 256 KB
  unsigned* partial1 = (unsigned*)(ws + (1 << 20));      // 16*144*1024*4 = 9.4 MB
  unsigned* partial3 = (unsigned*)(ws + (1 << 20) + (size_t)BB * CHUNKS * NBINS * 4);  // 9.4 MB
  (void)in_sizes; (void)n_in; (void)out_size; (void)ws_size;

  dim3 g1(CHUNKS, BB, 1);        // 2304 blocks, 8.3 KB LDS -> 6 blocks/CU (VGPR<=85)
  k_main<<<g1, 256, 0, stream>>>(logits, targets, mask, bce0g, partial1, partial3,
                                 flags, tickets);
  dim3 g2(NBINS / 64, BB, 1);    // 16 x 16 = 256 blocks
  k_tail<<<g2, 256, 0, stream>>>(partial1, partial3, flags, ghist, bce0g, acc,
                                 tickets, out);
}

// Round 15
// 169.470 us; speedup vs baseline: 1.0215x; 1.0215x over previous
//
#include <hip/hip_runtime.h>
#include <math.h>

#define BB 16
#define PP (768*768)        // 589824
#define NBINS 1024
#define CHUNKS 144          // blocks per image; pixels/block = 4096 exactly (no tail)
#define PIXB (PP / CHUNKS)  // 4096
#define PC4  (PIXB / 4)     // 1024 float4 per chunk = 4 * 256
#define KALL 176947         // int(P * 0.3)

#define LOV_LO (-17.0f)
#define LOV_RANGE 34.0f

typedef unsigned long long u64;

struct AccR { float lov_i, ft_i, ohem_i; unsigned posb; };                  // 16 B

__device__ inline float wred_sum(float v) {
  #pragma unroll
  for (int o = 32; o > 0; o >>= 1) v += __shfl_down(v, o, 64);
  return v;
}
__device__ inline float wred_max(float v) {
  #pragma unroll
  for (int o = 32; o > 0; o >>= 1) v = fmaxf(v, __shfl_down(v, o, 64));
  return v;
}

// ---------------- K1: histogram-only fused pass; 12 loads pinned in flight ----------------
// hist1[bin] = count | pos<<16
// hist3[bin] = #(t==0 && m!=1) | #(t==1 && m!=1)<<16   (atomic fires only when m!=1)
__global__ __launch_bounds__(256, 6) void k_main(const float* __restrict__ logits,
                                                 const int* __restrict__ targets,
                                                 const float* __restrict__ mask,
                                                 float* __restrict__ bce0g,
                                                 unsigned* __restrict__ partial1,
                                                 unsigned* __restrict__ partial3,
                                                 unsigned* __restrict__ flags,
                                                 unsigned* __restrict__ tickets)
{
  const int b = blockIdx.y;
  const int chunk = blockIdx.x;
  __shared__ unsigned hist1[NBINS];        // 4 KB
  __shared__ unsigned hist3[NBINS];        // 4 KB
  __shared__ unsigned s_any3;
  {  // uint4 zero-init: exactly one store per thread per array
    uint4 z; z.x = z.y = z.z = z.w = 0u;
    ((uint4*)hist1)[threadIdx.x] = z;
    ((uint4*)hist3)[threadIdx.x] = z;
  }
  if (threadIdx.x == 0) s_any3 = 0u;
  // zero tickets for k_tail (kernel-boundary ordering makes this safe)
  if (b == 0 && chunk == 0 && threadIdx.x < 32) tickets[threadIdx.x] = 0u;
  __syncthreads();

  const float4* l4 = (const float4*)(logits + (size_t)b * PP);
  const int4*   t4 = (const int4*)(targets + (size_t)b * PP);
  const float4* m4 = (const float4*)(mask + (size_t)b * PP);

  const float lov_scale = (float)NBINS / LOV_RANGE;

  // exact fallback loss_i[0]
  if (chunk == 0 && threadIdx.x == 0) {
    float l = logits[(size_t)b * PP];
    float tf = (float)targets[(size_t)b * PP];
    float m = mask[(size_t)b * PP];
    float ex = __expf(-fabsf(l));
    bce0g[b] = (fmaxf(l, 0.f) + __logf(1.f + ex) - l * tf) * m;
  }

  const int base4 = chunk * PC4;

  // ---- issue ALL 12 dwordx4 loads back-to-back ----
  float4 L[4]; int4 T[4]; float4 M[4];
  #pragma unroll
  for (int it = 0; it < 4; ++it) {
    int i = base4 + it * 256 + threadIdx.x;
    L[it] = l4[i]; T[it] = t4[i]; M[it] = m4[i];
  }
  // register tether: asm reads one component of each dwordx4 result so the
  // loads cannot be sunk below this point; one bulk s_waitcnt here.
  asm volatile("" ::
      "v"(L[0].x), "v"(L[1].x), "v"(L[2].x), "v"(L[3].x),
      "v"(T[0].x), "v"(T[1].x), "v"(T[2].x), "v"(T[3].x),
      "v"(M[0].x), "v"(M[1].x), "v"(M[2].x), "v"(M[3].x));

  unsigned bad = 0u;
  auto px = [&](float l, int ti, float m) {
    float s = fmaf(2.f, (float)ti, -1.f);
    float e = fmaf(-l, s, 1.f);                      // lovasz error
    int bin = (int)((e - LOV_LO) * lov_scale);
    bin = bin < 0 ? 0 : (bin > NBINS - 1 ? NBINS - 1 : bin);
    atomicAdd(&hist1[bin], 1u | ((unsigned)ti << 16));
    if (m != 1.0f) {                                 // never fires when mask==1
      bad = 1u;
      atomicAdd(&hist3[bin], ti ? 0x10000u : 1u);
    }
  };

  #pragma unroll
  for (int it = 0; it < 4; ++it) {
    px(L[it].x, T[it].x, M[it].x); px(L[it].y, T[it].y, M[it].y);
    px(L[it].z, T[it].z, M[it].z); px(L[it].w, T[it].w, M[it].w);
  }

  if (bad) s_any3 = 1u;     // benign race: all writers store 1
  __syncthreads();
  const unsigned any3 = s_any3;
  if (threadIdx.x == 0) flags[(size_t)b * CHUNKS + chunk] = any3;

  // non-atomic coalesced uint4 flush: one dwordx4 store per thread
  {
    uint4* d1 = (uint4*)(partial1 + ((size_t)b * CHUNKS + chunk) * NBINS);
    d1[threadIdx.x] = ((const uint4*)hist1)[threadIdx.x];
    if (any3) {
      uint4* d3 = (uint4*)(partial3 + ((size_t)b * CHUNKS + chunk) * NBINS);
      d3[threadIdx.x] = ((const uint4*)hist3)[threadIdx.x];
    }
  }
}

// ---------------- K2 (k_tail): branch-free slice reduce -> elected per-image scan -> combine ----------------
__global__ __launch_bounds__(256) void k_tail(const unsigned* __restrict__ partial1,
                                              const unsigned* __restrict__ partial3,
                                              const unsigned* __restrict__ flags,
                                              uint4* __restrict__ ghist,
                                              const float* __restrict__ bce0g,
                                              AccR* __restrict__ acc,
                                              unsigned* __restrict__ tickets,
                                              float* __restrict__ out)
{
  const int img = blockIdx.y;          // 16
  const int slice = blockIdx.x;        // NBINS/64 = 16 slices x 64 bins
  const int t = threadIdx.x;
  __shared__ unsigned sA[256], sB[256], sCc[256];
  __shared__ float sf[256], sg[256];
  __shared__ float wsum[4][6];
  __shared__ unsigned short s_list[CHUNKS];
  __shared__ int s_n;
  __shared__ unsigned s_do;
  __shared__ unsigned p_sh, ng_total_sh;
  __shared__ float pos_sh, tp_sh, spr_sh, mx_sh, npos_shf, nm0_shf;

  // ---- phase 1: branch-free reduce of this slice's 64 bins across 144 partials ----
  {
    const int lane = t & 63, g = t >> 6;           // 4 groups x 36 partials
    const int bin = slice * 64 + lane;
    const unsigned* s1 = partial1 + ((size_t)img * CHUNKS + (size_t)g * 36) * NBINS + bin;
    unsigned c = 0, q = 0;
    #pragma unroll 6
    for (int p = 0; p < 36; ++p) {
      unsigned v = s1[(size_t)p * NBINS];
      c += v & 0xFFFFu; q += v >> 16;
    }
    sA[t] = c; sB[t] = q;
    if (t == 0) s_n = 0;
    __syncthreads();

    // PARALLEL flag compaction (order-free: feeds an order-independent sum).
    // Replaces the 144-iteration serial t==0 global-load loop that cost
    // ~12-50 us of pure latency per block (R14's 48.5 us k_tail).
    if (t < CHUNKS) {
      if (flags[(size_t)img * CHUNKS + t]) {
        int idx = atomicAdd(&s_n, 1);
        s_list[idx] = (unsigned short)t;
      }
    }
    __syncthreads();

    if (t < 64) {
      unsigned ct = sA[t] + sA[64 + t] + sA[128 + t] + sA[192 + t];
      unsigned qt = sB[t] + sB[64 + t] + sB[128 + t] + sB[192 + t];
      const int bn = slice * 64 + t;
      unsigned a = 0, b2 = 0;
      const int n3 = s_n;                          // 0 when mask==1 everywhere
      for (int k = 0; k < n3; ++k) {
        int p = s_list[k];
        unsigned v = partial3[((size_t)img * CHUNKS + p) * NBINS + bn];
        a += v & 0xFFFFu; b2 += v >> 16;
      }
      uint4 o; o.x = ct; o.y = qt; o.z = a; o.w = b2;
      ghist[(size_t)img * NBINS + bn] = o;
    }
  }

  // ---- publish + elect: last slice-block of this image runs the scan ----
  __threadfence();
  __syncthreads();
  if (t == 0) {
    unsigned ret = atomicAdd(&tickets[img], 1u);
    s_do = (ret == (unsigned)(NBINS / 64) - 1) ? 1u : 0u;
  }
  __syncthreads();
  if (!s_do) return;
  __threadfence();   // acquire other slices' ghist writes

  // ---- phase 2: reconstruct sums + descending walk ----
  const float lov_d = LOV_RANGE / (float)NBINS;
  const uint4* gh = ghist + (size_t)img * NBINS;
  const int CH = NBINS / 256;          // 4 bins per thread

  uint4 loc[4];
  unsigned tc = 0, tq = 0, tn = 0;
  float pos_s = 0.f, tp_s = 0.f, spr_s = 0.f, mx_s = 0.f, npos_s = 0.f, nm0_s = 0.f;
  #pragma unroll
  for (int k = 0; k < 4; ++k) {
    int j = NBINS - 1 - (t * CH + k);
    uint4 v = gh[j]; loc[k] = v;
    unsigned c = v.x, q = v.y, a = v.z, b2 = v.w;
    tc += c; tq += q;
    unsigned ng = (c - q) - a;         // tissue negatives in bin
    tn += ng;
    npos_s += (float)(q - b2);         // tissue positives (exact integers)
    nm0_s  += (float)(a + b2);         // pixels with m != 1
    if (c) {
      float e = LOV_LO + ((float)j + 0.5f) * lov_d;
      float l1 = 1.f - e;              // logit for positives; negatives have l = -l1
      float ex = __expf(-fabsf(l1));
      float bceB = fmaxf(-l1, 0.f) + __logf(1.f + ex);   // softplus(e-1): loss for BOTH classes
      float sig1 = ((l1 >= 0.f) ? 1.f : ex) * __builtin_amdgcn_rcpf(1.f + ex);  // sigmoid(l1)
      unsigned qt = q - b2;
      pos_s = fmaf((float)qt, bceB, pos_s);
      tp_s  = fmaf((float)q, sig1, tp_s);
      spr_s = fmaf((float)q, sig1, spr_s);
      spr_s = fmaf((float)(c - q), 1.f - sig1, spr_s);
      if (qt + ng > 0) mx_s = fmaxf(mx_s, bceB);
    }
  }
  {
    float v0 = wred_sum(pos_s), v1 = wred_sum(tp_s), v2 = wred_sum(spr_s);
    float v3 = wred_max(mx_s), v4 = wred_sum(npos_s), v5 = wred_sum(nm0_s);
    int w = t >> 6, lane = t & 63;
    if (lane == 0) {
      wsum[w][0] = v0; wsum[w][1] = v1; wsum[w][2] = v2;
      wsum[w][3] = v3; wsum[w][4] = v4; wsum[w][5] = v5;
    }
  }
  sA[t] = tc; sB[t] = tq; sCc[t] = tn;
  __syncthreads();
  if (t == 0) {
    pos_sh = wsum[0][0] + wsum[1][0] + wsum[2][0] + wsum[3][0];
    tp_sh  = wsum[0][1] + wsum[1][1] + wsum[2][1] + wsum[3][1];
    spr_sh = wsum[0][2] + wsum[1][2] + wsum[2][2] + wsum[3][2];
    mx_sh  = fmaxf(fmaxf(wsum[0][3], wsum[1][3]), fmaxf(wsum[2][3], wsum[3][3]));
    npos_shf = wsum[0][4] + wsum[1][4] + wsum[2][4] + wsum[3][4];
    nm0_shf  = wsum[0][5] + wsum[1][5] + wsum[2][5] + wsum[3][5];
    unsigned aI = 0, aC = 0, aN = 0;
    for (int i = 0; i < 256; i++) {
      unsigned ci = sA[i], qi = sB[i], ni = sCc[i];
      sA[i] = aI; sB[i] = aC; sCc[i] = aN;
      aI += ci; aC += qi; aN += ni;
    }
    p_sh = aC; ng_total_sh = aN;
  }
  __syncthreads();

  const unsigned sum_t = p_sh;                 // total positives (unmasked), exact
  const float p = (float)sum_t;
  const bool has_pos = sum_t > 0;
  const unsigned n_neg_total = (unsigned)PP - sum_t;
  int n_pos = (int)npos_shf;                   // tissue positives, exact
  int n_remain = KALL - n_pos; if (n_remain < 0) n_remain = 0;

  float lov_local = 0.f, ns_local = 0.f;
  {
    unsigned I = sA[t], C = sB[t], NG = sCc[t];
    float Jprev = has_pos ? (1.f - (p - (float)C) / (p + (float)I - (float)C)) : 0.f;
    #pragma unroll
    for (int k = 0; k < 4; ++k) {
      int j = NBINS - 1 - (t * CH + k);
      uint4 v = loc[k];
      unsigned c = v.x;
      if (c) {
        unsigned q = v.y;
        unsigned ng = (c - q) - v.z;
        float e = LOV_LO + ((float)j + 0.5f) * lov_d;
        if (has_pos) {
          float re = fmaxf(e, 0.f);
          if (n_neg_total > 0) {
            I += c; C += q;
            float Jb = 1.f - (p - (float)C) / (p + (float)I - (float)C);
            lov_local += re * (Jb - Jprev);
            Jprev = Jb;
          } else {
            double hi = (double)I + (double)c;
            double s = (hi * (hi + 1.0) - (double)I * ((double)I + 1.0)) * 0.5 / (double)p;
            lov_local += re * (float)s;
            I += c;
          }
        }
        if (n_remain > 0 && ng) {
          long long rem = (long long)n_remain - (long long)NG;
          unsigned take = rem <= 0 ? 0u : (rem >= (long long)ng ? ng : (unsigned)rem);
          if (take) {
            float l = e - 1.f;                         // negatives: e = 1 + l
            float nloss = fmaxf(l, 0.f) + __logf(1.f + __expf(-fabsf(l)));
            ns_local += (float)take * nloss;
          }
          NG += ng;
        }
      }
    }
  }
  sf[t] = lov_local; sg[t] = ns_local; __syncthreads();
  for (int off = 128; off > 0; off >>= 1) {
    if (t < off) { sf[t] += sf[t + off]; sg[t] += sg[t + off]; }
    __syncthreads();
  }

  if (t == 0) {
    float lov = sf[0];
    float neg_sum = sg[0];
    unsigned kept = (n_remain > 0)
        ? ((unsigned)n_remain < ng_total_sh ? (unsigned)n_remain : ng_total_sh) : 0u;
    float cnt = (float)n_pos + (float)kept;
    float ohem;
    if (cnt > 0.f) ohem = (pos_sh + neg_sum) / cnt;
    else ohem = ((float)PP - nm0_shf > 0.f) ? mx_sh : bce0g[img];
    float tp = tp_sh;
    float fn = p - tp;
    float fp = spr_sh - tp;
    float tv = (tp + 1e-6f) / (tp + 0.3f * fn + 0.7f * fp + 1e-6f);
    float ft = powf(fmaxf(1.f - tv, 0.f), 1.33f);
    acc[img].lov_i = lov; acc[img].ft_i = ft; acc[img].ohem_i = ohem;
    acc[img].posb = has_pos ? 1u : 0u;

    __threadfence();
    unsigned ret = atomicAdd(&tickets[16], 1u);
    if (ret == BB - 1) {                 // last image: final combine
      __threadfence();
      volatile AccR* va = acc;
      float os = 0.f, fts = 0.f, lvs = 0.f; int np = 0;
      for (int i = 0; i < BB; i++) {
        os += va[i].ohem_i;
        if (va[i].posb) { np++; fts += va[i].ft_i; lvs += va[i].lov_i; }
      }
      float denom = (np > 0) ? (float)np : 1.f;
      float r = os / (float)BB;
      if (np > 0) r += fts / denom + 0.2f * (lvs / denom);
      out[0] = r;
    }
  }
}

extern "C" void kernel_launch(void* const* d_in, const int* in_sizes, int n_in,
                              void* d_out, int out_size, void* d_ws, size_t ws_size,
                              hipStream_t stream) {
  const float* logits  = (const float*)d_in[0];
  const int*   targets = (const int*)d_in[1];
  const float* mask    = (const float*)d_in[2];
  float* out = (float*)d_out;

  char* ws = (char*)d_ws;
  AccR*     acc      = (AccR*)ws;                        // 256 B
  unsigned* tickets  = (unsigned*)(ws + 256);            // 32 u32
  float*    bce0g    = (float*)(ws + 512);               // 64 B
  unsigned* flags    = (unsigned*)(ws + 4096);           // 16*144*4 = 9.2 KB
  uint4*    ghist    = (uint4*)(ws + (64 << 10));        // 16*1024*16 = 256 KB
  unsigned* partial1 = (unsigned*)(ws + (1 << 20));      // 16*144*1024*4 = 9.4 MB
  unsigned* partial3 = (unsigned*)(ws + (1 << 20) + (size_t)BB * CHUNKS * NBINS * 4);  // 9.4 MB
  (void)in_sizes; (void)n_in; (void)out_size; (void)ws_size;

  dim3 g1(CHUNKS, BB, 1);        // 2304 blocks, 8.3 KB LDS -> 6 blocks/CU (VGPR<=85)
  k_main<<<g1, 256, 0, stream>>>(logits, targets, mask, bce0g, partial1, partial3,
                                 flags, tickets);
  dim3 g2(NBINS / 64, BB, 1);    // 16 x 16 = 256 blocks
  k_tail<<<g2, 256, 0, stream>>>(partial1, partial3, flags, ghist, bce0g, acc,
                                 tickets, out);
}

// Round 16
// 151.456 us; speedup vs baseline: 1.1430x; 1.1189x over previous
//
#include <hip/hip_runtime.h>
#include <math.h>

#define BB 16
#define PP (768*768)        // 589824
#define NBINS 1024
#define CHUNKS 144          // blocks per image; pixels/block = 4096 exactly (no tail)
#define PIXB (PP / CHUNKS)  // 4096
#define PC4  (PIXB / 4)     // 1024 float4 per chunk = 4 * 256
#define KALL 176947         // int(P * 0.3)

#define LOV_LO (-17.0f)
#define LOV_RANGE 34.0f

typedef unsigned long long u64;

struct AccR { float lov_i, ft_i, ohem_i; unsigned posb; };                  // 16 B

__device__ inline float wred_sum(float v) {
  #pragma unroll
  for (int o = 32; o > 0; o >>= 1) v += __shfl_down(v, o, 64);
  return v;
}
__device__ inline float wred_max(float v) {
  #pragma unroll
  for (int o = 32; o > 0; o >>= 1) v = fmaxf(v, __shfl_down(v, o, 64));
  return v;
}

// ---------------- K1: histogram-only fused pass; 12 loads pinned in flight ----------------
// hist1[bin] = count | pos<<16
// hist3[bin] = #(t==0 && m!=1) | #(t==1 && m!=1)<<16   (atomic fires only when m!=1)
__global__ __launch_bounds__(256, 6) void k_main(const float* __restrict__ logits,
                                                 const int* __restrict__ targets,
                                                 const float* __restrict__ mask,
                                                 float* __restrict__ bce0g,
                                                 unsigned* __restrict__ partial1,
                                                 unsigned* __restrict__ partial3,
                                                 unsigned* __restrict__ flags)
{
  const int b = blockIdx.y;
  const int chunk = blockIdx.x;
  __shared__ unsigned hist1[NBINS];        // 4 KB
  __shared__ unsigned hist3[NBINS];        // 4 KB
  __shared__ unsigned s_any3;
  {  // uint4 zero-init: exactly one store per thread per array
    uint4 z; z.x = z.y = z.z = z.w = 0u;
    ((uint4*)hist1)[threadIdx.x] = z;
    ((uint4*)hist3)[threadIdx.x] = z;
  }
  if (threadIdx.x == 0) s_any3 = 0u;
  __syncthreads();

  const float4* l4 = (const float4*)(logits + (size_t)b * PP);
  const int4*   t4 = (const int4*)(targets + (size_t)b * PP);
  const float4* m4 = (const float4*)(mask + (size_t)b * PP);

  const float lov_scale = (float)NBINS / LOV_RANGE;

  // exact fallback loss_i[0]
  if (chunk == 0 && threadIdx.x == 0) {
    float l = logits[(size_t)b * PP];
    float tf = (float)targets[(size_t)b * PP];
    float m = mask[(size_t)b * PP];
    float ex = __expf(-fabsf(l));
    bce0g[b] = (fmaxf(l, 0.f) + __logf(1.f + ex) - l * tf) * m;
  }

  const int base4 = chunk * PC4;

  // ---- issue ALL 12 dwordx4 loads back-to-back ----
  float4 L[4]; int4 T[4]; float4 M[4];
  #pragma unroll
  for (int it = 0; it < 4; ++it) {
    int i = base4 + it * 256 + threadIdx.x;
    L[it] = l4[i]; T[it] = t4[i]; M[it] = m4[i];
  }
  // register tether: asm reads one component of each dwordx4 result so the
  // loads cannot be sunk below this point; one bulk s_waitcnt here.
  asm volatile("" ::
      "v"(L[0].x), "v"(L[1].x), "v"(L[2].x), "v"(L[3].x),
      "v"(T[0].x), "v"(T[1].x), "v"(T[2].x), "v"(T[3].x),
      "v"(M[0].x), "v"(M[1].x), "v"(M[2].x), "v"(M[3].x));

  unsigned bad = 0u;
  auto px = [&](float l, int ti, float m) {
    float s = fmaf(2.f, (float)ti, -1.f);
    float e = fmaf(-l, s, 1.f);                      // lovasz error
    int bin = (int)((e - LOV_LO) * lov_scale);
    bin = bin < 0 ? 0 : (bin > NBINS - 1 ? NBINS - 1 : bin);
    atomicAdd(&hist1[bin], 1u | ((unsigned)ti << 16));
    if (m != 1.0f) {                                 // never fires when mask==1
      bad = 1u;
      atomicAdd(&hist3[bin], ti ? 0x10000u : 1u);
    }
  };

  #pragma unroll
  for (int it = 0; it < 4; ++it) {
    px(L[it].x, T[it].x, M[it].x); px(L[it].y, T[it].y, M[it].y);
    px(L[it].z, T[it].z, M[it].z); px(L[it].w, T[it].w, M[it].w);
  }

  if (bad) s_any3 = 1u;     // benign race: all writers store 1
  __syncthreads();
  const unsigned any3 = s_any3;
  if (threadIdx.x == 0) flags[(size_t)b * CHUNKS + chunk] = any3;

  // non-atomic coalesced uint4 flush: one dwordx4 store per thread
  {
    uint4* d1 = (uint4*)(partial1 + ((size_t)b * CHUNKS + chunk) * NBINS);
    d1[threadIdx.x] = ((const uint4*)hist1)[threadIdx.x];
    if (any3) {
      uint4* d3 = (uint4*)(partial3 + ((size_t)b * CHUNKS + chunk) * NBINS);
      d3[threadIdx.x] = ((const uint4*)hist3)[threadIdx.x];
    }
  }
}

// ---------------- K1b: branch-free partial reduce -> uint4 ghist; zero ticket ----------------
// No device-scope fences here (the R14/R15 fused-tail fence storm cost ~45 us).
__global__ __launch_bounds__(256) void k_reduce(const unsigned* __restrict__ partial1,
                                                const unsigned* __restrict__ partial3,
                                                const unsigned* __restrict__ flags,
                                                uint4* __restrict__ ghist,
                                                unsigned* __restrict__ tickets)
{
  const int img = blockIdx.y;          // 16
  const int slice = blockIdx.x;        // NBINS/64 = 16 slices x 64 bins
  const int t = threadIdx.x;
  const int lane = t & 63, g = t >> 6;           // 4 groups x 36 partials
  const int bin = slice * 64 + lane;
  __shared__ unsigned sC[256], sQ[256];
  __shared__ unsigned short s_list[CHUNKS];
  __shared__ int s_n;

  if (t == 0) s_n = 0;

  // hot loop: 36 strided loads, no branches
  const unsigned* s1 = partial1 + ((size_t)img * CHUNKS + (size_t)g * 36) * NBINS + bin;
  unsigned c = 0, q = 0;
  #pragma unroll 6
  for (int p = 0; p < 36; ++p) {
    unsigned v = s1[(size_t)p * NBINS];
    c += v & 0xFFFFu; q += v >> 16;
  }
  sC[t] = c; sQ[t] = q;
  __syncthreads();

  // PARALLEL flag compaction (order-free: feeds an order-independent sum).
  // Replaces the serial t==0 144-global-load loop (~25-35 us of pure latency).
  if (t < CHUNKS) {
    if (flags[(size_t)img * CHUNKS + t]) {
      int idx = atomicAdd(&s_n, 1);
      s_list[idx] = (unsigned short)t;
    }
  }
  __syncthreads();

  if (t < 64) {
    unsigned ct = sC[t] + sC[64 + t] + sC[128 + t] + sC[192 + t];
    unsigned qt = sQ[t] + sQ[64 + t] + sQ[128 + t] + sQ[192 + t];
    const int bn = slice * 64 + t;
    unsigned a = 0, b2 = 0;
    const int n3 = s_n;                          // 0 when mask==1 everywhere
    for (int k = 0; k < n3; ++k) {
      int p = s_list[k];
      unsigned v = partial3[((size_t)img * CHUNKS + p) * NBINS + bn];
      a += v & 0xFFFFu; b2 += v >> 16;
    }
    uint4 o; o.x = ct; o.y = qt; o.z = a; o.w = b2;
    ghist[(size_t)img * NBINS + bn] = o;
  }
  if (slice == 0 && img == 0 && t == 0) tickets[0] = 0u;
}

// ---------------- K2: reconstruct sums from hist + descending walk + final combine ----------------
__global__ __launch_bounds__(256) void k_scan(const uint4* __restrict__ ghist,
                                              const float* __restrict__ bce0g,
                                              AccR* __restrict__ acc,
                                              unsigned* __restrict__ tickets,
                                              float* __restrict__ out)
{
  const int b = blockIdx.x;
  const int t = threadIdx.x;
  __shared__ unsigned sA[256], sB[256], sC[256];
  __shared__ float sf[256], sg[256];
  __shared__ float wsum[4][6];
  __shared__ unsigned p_sh, ng_total_sh;
  __shared__ float pos_sh, tp_sh, spr_sh, mx_sh, npos_shf, nm0_shf;

  const float lov_d = LOV_RANGE / (float)NBINS;
  const uint4* gh = ghist + (size_t)b * NBINS;
  const int CH = NBINS / 256;          // 4 bins per thread

  // ---- pass 1: load (descending), per-thread sums + scalar reconstruction ----
  uint4 loc[4];
  unsigned tc = 0, tq = 0, tn = 0;
  float pos_s = 0.f, tp_s = 0.f, spr_s = 0.f, mx_s = 0.f, npos_s = 0.f, nm0_s = 0.f;
  #pragma unroll
  for (int k = 0; k < 4; ++k) {
    int j = NBINS - 1 - (t * CH + k);
    uint4 v = gh[j]; loc[k] = v;
    unsigned c = v.x, q = v.y, a = v.z, b2 = v.w;
    tc += c; tq += q;
    unsigned ng = (c - q) - a;         // tissue negatives in bin
    tn += ng;
    npos_s += (float)(q - b2);         // tissue positives (exact integers)
    nm0_s  += (float)(a + b2);         // pixels with m != 1
    if (c) {
      float e = LOV_LO + ((float)j + 0.5f) * lov_d;
      float l1 = 1.f - e;              // logit for positives; negatives have l = -l1
      float ex = __expf(-fabsf(l1));
      float bceB = fmaxf(-l1, 0.f) + __logf(1.f + ex);   // softplus(e-1): loss for BOTH classes
      float sig1 = ((l1 >= 0.f) ? 1.f : ex) * __builtin_amdgcn_rcpf(1.f + ex);  // sigmoid(l1)
      unsigned qt = q - b2;
      pos_s = fmaf((float)qt, bceB, pos_s);
      tp_s  = fmaf((float)q, sig1, tp_s);
      spr_s = fmaf((float)q, sig1, spr_s);
      spr_s = fmaf((float)(c - q), 1.f - sig1, spr_s);
      if (qt + ng > 0) mx_s = fmaxf(mx_s, bceB);
    }
  }
  {
    float v0 = wred_sum(pos_s), v1 = wred_sum(tp_s), v2 = wred_sum(spr_s);
    float v3 = wred_max(mx_s), v4 = wred_sum(npos_s), v5 = wred_sum(nm0_s);
    int w = t >> 6, lane = t & 63;
    if (lane == 0) {
      wsum[w][0] = v0; wsum[w][1] = v1; wsum[w][2] = v2;
      wsum[w][3] = v3; wsum[w][4] = v4; wsum[w][5] = v5;
    }
  }
  sA[t] = tc; sB[t] = tq; sC[t] = tn;
  __syncthreads();
  if (t == 0) {
    pos_sh = wsum[0][0] + wsum[1][0] + wsum[2][0] + wsum[3][0];
    tp_sh  = wsum[0][1] + wsum[1][1] + wsum[2][1] + wsum[3][1];
    spr_sh = wsum[0][2] + wsum[1][2] + wsum[2][2] + wsum[3][2];
    mx_sh  = fmaxf(fmaxf(wsum[0][3], wsum[1][3]), fmaxf(wsum[2][3], wsum[3][3]));
    npos_shf = wsum[0][4] + wsum[1][4] + wsum[2][4] + wsum[3][4];
    nm0_shf  = wsum[0][5] + wsum[1][5] + wsum[2][5] + wsum[3][5];
    unsigned aI = 0, aC = 0, aN = 0;
    for (int i = 0; i < 256; i++) {
      unsigned ci = sA[i], qi = sB[i], ni = sC[i];
      sA[i] = aI; sB[i] = aC; sC[i] = aN;
      aI += ci; aC += qi; aN += ni;
    }
    p_sh = aC; ng_total_sh = aN;
  }
  __syncthreads();

  const unsigned sum_t = p_sh;                 // total positives (unmasked), exact
  const float p = (float)sum_t;
  const bool has_pos = sum_t > 0;
  const unsigned n_neg_total = (unsigned)PP - sum_t;
  int n_pos = (int)npos_shf;                   // tissue positives, exact
  int n_remain = KALL - n_pos; if (n_remain < 0) n_remain = 0;

  // ---- pass 2: descending walk (lovasz + OHEM top-k) ----
  float lov_local = 0.f, ns_local = 0.f;
  {
    unsigned I = sA[t], C = sB[t], NG = sC[t];
    float Jprev = has_pos ? (1.f - (p - (float)C) / (p + (float)I - (float)C)) : 0.f;
    #pragma unroll
    for (int k = 0; k < 4; ++k) {
      int j = NBINS - 1 - (t * CH + k);
      uint4 v = loc[k];
      unsigned c = v.x;
      if (c) {
        unsigned q = v.y;
        unsigned ng = (c - q) - v.z;
        float e = LOV_LO + ((float)j + 0.5f) * lov_d;
        if (has_pos) {
          float re = fmaxf(e, 0.f);
          if (n_neg_total > 0) {
            I += c; C += q;
            float Jb = 1.f - (p - (float)C) / (p + (float)I - (float)C);
            lov_local += re * (Jb - Jprev);
            Jprev = Jb;
          } else {
            double hi = (double)I + (double)c;
            double s = (hi * (hi + 1.0) - (double)I * ((double)I + 1.0)) * 0.5 / (double)p;
            lov_local += re * (float)s;
            I += c;
          }
        }
        if (n_remain > 0 && ng) {
          long long rem = (long long)n_remain - (long long)NG;
          unsigned take = rem <= 0 ? 0u : (rem >= (long long)ng ? ng : (unsigned)rem);
          if (take) {
            float l = e - 1.f;                         // negatives: e = 1 + l
            float nloss = fmaxf(l, 0.f) + __logf(1.f + __expf(-fabsf(l)));
            ns_local += (float)take * nloss;
          }
          NG += ng;
        }
      }
    }
  }
  sf[t] = lov_local; sg[t] = ns_local; __syncthreads();
  for (int off = 128; off > 0; off >>= 1) {
    if (t < off) { sf[t] += sf[t + off]; sg[t] += sg[t + off]; }
    __syncthreads();
  }

  if (t == 0) {
    float lov = sf[0];
    float neg_sum = sg[0];
    unsigned kept = (n_remain > 0)
        ? ((unsigned)n_remain < ng_total_sh ? (unsigned)n_remain : ng_total_sh) : 0u;
    float cnt = (float)n_pos + (float)kept;
    float ohem;
    if (cnt > 0.f) ohem = (pos_sh + neg_sum) / cnt;
    else ohem = ((float)PP - nm0_shf > 0.f) ? mx_sh : bce0g[b];
    float tp = tp_sh;
    float fn = p - tp;
    float fp = spr_sh - tp;
    float tv = (tp + 1e-6f) / (tp + 0.3f * fn + 0.7f * fp + 1e-6f);
    float ft = powf(fmaxf(1.f - tv, 0.f), 1.33f);
    acc[b].lov_i = lov; acc[b].ft_i = ft; acc[b].ohem_i = ohem;
    acc[b].posb = has_pos ? 1u : 0u;

    __threadfence();
    unsigned ret = atomicAdd(&tickets[0], 1u);
    if (ret == BB - 1) {                 // last image: final combine
      __threadfence();
      volatile AccR* va = acc;
      float os = 0.f, fts = 0.f, lvs = 0.f; int np = 0;
      for (int i = 0; i < BB; i++) {
        os += va[i].ohem_i;
        if (va[i].posb) { np++; fts += va[i].ft_i; lvs += va[i].lov_i; }
      }
      float denom = (np > 0) ? (float)np : 1.f;
      float r = os / (float)BB;
      if (np > 0) r += fts / denom + 0.2f * (lvs / denom);
      out[0] = r;
    }
  }
}

extern "C" void kernel_launch(void* const* d_in, const int* in_sizes, int n_in,
                              void* d_out, int out_size, void* d_ws, size_t ws_size,
                              hipStream_t stream) {
  const float* logits  = (const float*)d_in[0];
  const int*   targets = (const int*)d_in[1];
  const float* mask    = (const float*)d_in[2];
  float* out = (float*)d_out;

  char* ws = (char*)d_ws;
  AccR*     acc      = (AccR*)ws;                        // 256 B
  unsigned* tickets  = (unsigned*)(ws + 256);            // u32
  float*    bce0g    = (float*)(ws + 512);               // 64 B
  unsigned* flags    = (unsigned*)(ws + 4096);           // 16*144*4 = 9.2 KB
  uint4*    ghist    = (uint4*)(ws + (64 << 10));        // 16*1024*16 = 256 KB
  unsigned* partial1 = (unsigned*)(ws + (1 << 20));      // 16*144*1024*4 = 9.4 MB
  unsigned* partial3 = (unsigned*)(ws + (1 << 20) + (size_t)BB * CHUNKS * NBINS * 4);  // 9.4 MB
  (void)in_sizes; (void)n_in; (void)out_size; (void)ws_size;

  dim3 g1(CHUNKS, BB, 1);        // 2304 blocks, 8.3 KB LDS -> 6 blocks/CU (VGPR<=85)
  k_main<<<g1, 256, 0, stream>>>(logits, targets, mask, bce0g, partial1, partial3, flags);
  dim3 g2(NBINS / 64, BB, 1);    // 16 x 16 = 256 blocks
  k_reduce<<<g2, 256, 0, stream>>>(partial1, partial3, flags, ghist, tickets);
  k_scan<<<BB, 256, 0, stream>>>(ghist, bce0g, acc, tickets, out);
}

// Round 17
// 150.605 us; speedup vs baseline: 1.1495x; 1.0057x over previous
//
#include <hip/hip_runtime.h>
#include <math.h>

#define BB 16
#define PP (768*768)        // 589824
#define NBINS 1024
#define CHUNKS 144          // blocks per image; pixels/block = 4096 exactly (no tail)
#define PIXB (PP / CHUNKS)  // 4096
#define PC4  (PIXB / 4)     // 1024 float4 per chunk = 4 * 256
#define KALL 176947         // int(P * 0.3)

#define LOV_LO (-17.0f)
#define LOV_RANGE 34.0f

typedef unsigned long long u64;

struct AccR { float lov_i, ft_i, ohem_i; unsigned posb; };                  // 16 B

__device__ inline float wred_sum(float v) {
  #pragma unroll
  for (int o = 32; o > 0; o >>= 1) v += __shfl_down(v, o, 64);
  return v;
}
__device__ inline float wred_max(float v) {
  #pragma unroll
  for (int o = 32; o > 0; o >>= 1) v = fmaxf(v, __shfl_down(v, o, 64));
  return v;
}

// ---------------- K1: histogram-only fused pass; split-tether 2-stage pipeline ----------------
// hist1[bin] = count | pos<<16
// hist3[bin] = #(t==0 && m!=1) | #(t==1 && m!=1)<<16   (atomic fires only when m!=1)
__global__ __launch_bounds__(256, 6) void k_main(const float* __restrict__ logits,
                                                 const int* __restrict__ targets,
                                                 const float* __restrict__ mask,
                                                 float* __restrict__ bce0g,
                                                 unsigned* __restrict__ partial1,
                                                 unsigned* __restrict__ partial3,
                                                 unsigned* __restrict__ flags)
{
  const int b = blockIdx.y;
  const int chunk = blockIdx.x;
  __shared__ unsigned hist1[NBINS];        // 4 KB
  __shared__ unsigned hist3[NBINS];        // 4 KB
  __shared__ unsigned s_any3;
  {  // uint4 zero-init: exactly one store per thread per array
    uint4 z; z.x = z.y = z.z = z.w = 0u;
    ((uint4*)hist1)[threadIdx.x] = z;
    ((uint4*)hist3)[threadIdx.x] = z;
  }
  if (threadIdx.x == 0) s_any3 = 0u;
  __syncthreads();

  const float4* l4 = (const float4*)(logits + (size_t)b * PP);
  const int4*   t4 = (const int4*)(targets + (size_t)b * PP);
  const float4* m4 = (const float4*)(mask + (size_t)b * PP);

  const float lov_scale = (float)NBINS / LOV_RANGE;

  // exact fallback loss_i[0]
  if (chunk == 0 && threadIdx.x == 0) {
    float l = logits[(size_t)b * PP];
    float tf = (float)targets[(size_t)b * PP];
    float m = mask[(size_t)b * PP];
    float ex = __expf(-fabsf(l));
    bce0g[b] = (fmaxf(l, 0.f) + __logf(1.f + ex) - l * tf) * m;
  }

  const int base4 = chunk * PC4;

  // ---- issue ALL 12 dwordx4 loads back-to-back ----
  float4 L[4]; int4 T[4]; float4 M[4];
  #pragma unroll
  for (int it = 0; it < 4; ++it) {
    int i = base4 + it * 256 + threadIdx.x;
    L[it] = l4[i]; T[it] = t4[i]; M[it] = m4[i];
  }

  unsigned bad = 0u;
  auto px = [&](float l, int ti, float m) {
    float s = fmaf(2.f, (float)ti, -1.f);
    float e = fmaf(-l, s, 1.f);                      // lovasz error
    int bin = (int)((e - LOV_LO) * lov_scale);
    bin = bin < 0 ? 0 : (bin > NBINS - 1 ? NBINS - 1 : bin);
    atomicAdd(&hist1[bin], 1u | ((unsigned)ti << 16));
    if (m != 1.0f) {                                 // never fires when mask==1
      bad = 1u;
      atomicAdd(&hist3[bin], ti ? 0x10000u : 1u);
    }
  };

  // ---- stage A tether: wait only for the 6 oldest loads (vmcnt(6)); the
  // "memory" clobber pins stage-B loads above this point so they stay in
  // flight while we process stage A's 8 pixels. Split-tether pipeline:
  // compute overlaps the second half of the memory latency.
  asm volatile("" ::
      "v"(L[0].x), "v"(L[1].x), "v"(T[0].x), "v"(T[1].x),
      "v"(M[0].x), "v"(M[1].x) : "memory");
  #pragma unroll
  for (int it = 0; it < 2; ++it) {
    px(L[it].x, T[it].x, M[it].x); px(L[it].y, T[it].y, M[it].y);
    px(L[it].z, T[it].z, M[it].z); px(L[it].w, T[it].w, M[it].w);
  }
  // ---- stage B tether + process ----
  asm volatile("" ::
      "v"(L[2].x), "v"(L[3].x), "v"(T[2].x), "v"(T[3].x),
      "v"(M[2].x), "v"(M[3].x) : "memory");
  #pragma unroll
  for (int it = 2; it < 4; ++it) {
    px(L[it].x, T[it].x, M[it].x); px(L[it].y, T[it].y, M[it].y);
    px(L[it].z, T[it].z, M[it].z); px(L[it].w, T[it].w, M[it].w);
  }

  if (bad) s_any3 = 1u;     // benign race: all writers store 1
  __syncthreads();
  const unsigned any3 = s_any3;
  if (threadIdx.x == 0) flags[(size_t)b * CHUNKS + chunk] = any3;

  // non-atomic coalesced uint4 flush: one dwordx4 store per thread
  {
    uint4* d1 = (uint4*)(partial1 + ((size_t)b * CHUNKS + chunk) * NBINS);
    d1[threadIdx.x] = ((const uint4*)hist1)[threadIdx.x];
    if (any3) {
      uint4* d3 = (uint4*)(partial3 + ((size_t)b * CHUNKS + chunk) * NBINS);
      d3[threadIdx.x] = ((const uint4*)hist3)[threadIdx.x];
    }
  }
}

// ---------------- K1b: branch-free partial reduce -> uint4 ghist; zero ticket ----------------
// No device-scope fences here (the R14/R15 fused-tail fence storm cost ~45 us).
__global__ __launch_bounds__(256) void k_reduce(const unsigned* __restrict__ partial1,
                                                const unsigned* __restrict__ partial3,
                                                const unsigned* __restrict__ flags,
                                                uint4* __restrict__ ghist,
                                                unsigned* __restrict__ tickets)
{
  const int img = blockIdx.y;          // 16
  const int slice = blockIdx.x;        // NBINS/64 = 16 slices x 64 bins
  const int t = threadIdx.x;
  const int lane = t & 63, g = t >> 6;           // 4 groups x 36 partials
  const int bin = slice * 64 + lane;
  __shared__ unsigned sC[256], sQ[256];
  __shared__ unsigned short s_list[CHUNKS];
  __shared__ int s_n;

  if (t == 0) s_n = 0;

  // hot loop: 36 strided loads, no branches
  const unsigned* s1 = partial1 + ((size_t)img * CHUNKS + (size_t)g * 36) * NBINS + bin;
  unsigned c = 0, q = 0;
  #pragma unroll 6
  for (int p = 0; p < 36; ++p) {
    unsigned v = s1[(size_t)p * NBINS];
    c += v & 0xFFFFu; q += v >> 16;
  }
  sC[t] = c; sQ[t] = q;
  __syncthreads();

  // PARALLEL flag compaction (order-free: feeds an order-independent sum).
  if (t < CHUNKS) {
    if (flags[(size_t)img * CHUNKS + t]) {
      int idx = atomicAdd(&s_n, 1);
      s_list[idx] = (unsigned short)t;
    }
  }
  __syncthreads();

  if (t < 64) {
    unsigned ct = sC[t] + sC[64 + t] + sC[128 + t] + sC[192 + t];
    unsigned qt = sQ[t] + sQ[64 + t] + sQ[128 + t] + sQ[192 + t];
    const int bn = slice * 64 + t;
    unsigned a = 0, b2 = 0;
    const int n3 = s_n;                          // 0 when mask==1 everywhere
    for (int k = 0; k < n3; ++k) {
      int p = s_list[k];
      unsigned v = partial3[((size_t)img * CHUNKS + p) * NBINS + bn];
      a += v & 0xFFFFu; b2 += v >> 16;
    }
    uint4 o; o.x = ct; o.y = qt; o.z = a; o.w = b2;
    ghist[(size_t)img * NBINS + bn] = o;
  }
  if (slice == 0 && img == 0 && t == 0) tickets[0] = 0u;
}

// ---------------- K2: reconstruct sums from hist + descending walk + final combine ----------------
__global__ __launch_bounds__(256) void k_scan(const uint4* __restrict__ ghist,
                                              const float* __restrict__ bce0g,
                                              AccR* __restrict__ acc,
                                              unsigned* __restrict__ tickets,
                                              float* __restrict__ out)
{
  const int b = blockIdx.x;
  const int t = threadIdx.x;
  __shared__ unsigned sA[256], sB[256], sC[256];
  __shared__ float sf[256], sg[256];
  __shared__ float wsum[4][6];
  __shared__ unsigned p_sh, ng_total_sh;
  __shared__ float pos_sh, tp_sh, spr_sh, mx_sh, npos_shf, nm0_shf;

  const float lov_d = LOV_RANGE / (float)NBINS;
  const uint4* gh = ghist + (size_t)b * NBINS;
  const int CH = NBINS / 256;          // 4 bins per thread

  // ---- pass 1: load (descending), per-thread sums + scalar reconstruction ----
  uint4 loc[4];
  unsigned tc = 0, tq = 0, tn = 0;
  float pos_s = 0.f, tp_s = 0.f, spr_s = 0.f, mx_s = 0.f, npos_s = 0.f, nm0_s = 0.f;
  #pragma unroll
  for (int k = 0; k < 4; ++k) {
    int j = NBINS - 1 - (t * CH + k);
    uint4 v = gh[j]; loc[k] = v;
    unsigned c = v.x, q = v.y, a = v.z, b2 = v.w;
    tc += c; tq += q;
    unsigned ng = (c - q) - a;         // tissue negatives in bin
    tn += ng;
    npos_s += (float)(q - b2);         // tissue positives (exact integers)
    nm0_s  += (float)(a + b2);         // pixels with m != 1
    if (c) {
      float e = LOV_LO + ((float)j + 0.5f) * lov_d;
      float l1 = 1.f - e;              // logit for positives; negatives have l = -l1
      float ex = __expf(-fabsf(l1));
      float bceB = fmaxf(-l1, 0.f) + __logf(1.f + ex);   // softplus(e-1): loss for BOTH classes
      float sig1 = ((l1 >= 0.f) ? 1.f : ex) * __builtin_amdgcn_rcpf(1.f + ex);  // sigmoid(l1)
      unsigned qt = q - b2;
      pos_s = fmaf((float)qt, bceB, pos_s);
      tp_s  = fmaf((float)q, sig1, tp_s);
      spr_s = fmaf((float)q, sig1, spr_s);
      spr_s = fmaf((float)(c - q), 1.f - sig1, spr_s);
      if (qt + ng > 0) mx_s = fmaxf(mx_s, bceB);
    }
  }
  {
    float v0 = wred_sum(pos_s), v1 = wred_sum(tp_s), v2 = wred_sum(spr_s);
    float v3 = wred_max(mx_s), v4 = wred_sum(npos_s), v5 = wred_sum(nm0_s);
    int w = t >> 6, lane = t & 63;
    if (lane == 0) {
      wsum[w][0] = v0; wsum[w][1] = v1; wsum[w][2] = v2;
      wsum[w][3] = v3; wsum[w][4] = v4; wsum[w][5] = v5;
    }
  }
  sA[t] = tc; sB[t] = tq; sC[t] = tn;
  __syncthreads();
  if (t == 0) {
    pos_sh = wsum[0][0] + wsum[1][0] + wsum[2][0] + wsum[3][0];
    tp_sh  = wsum[0][1] + wsum[1][1] + wsum[2][1] + wsum[3][1];
    spr_sh = wsum[0][2] + wsum[1][2] + wsum[2][2] + wsum[3][2];
    mx_sh  = fmaxf(fmaxf(wsum[0][3], wsum[1][3]), fmaxf(wsum[2][3], wsum[3][3]));
    npos_shf = wsum[0][4] + wsum[1][4] + wsum[2][4] + wsum[3][4];
    nm0_shf  = wsum[0][5] + wsum[1][5] + wsum[2][5] + wsum[3][5];
    unsigned aI = 0, aC = 0, aN = 0;
    for (int i = 0; i < 256; i++) {
      unsigned ci = sA[i], qi = sB[i], ni = sC[i];
      sA[i] = aI; sB[i] = aC; sC[i] = aN;
      aI += ci; aC += qi; aN += ni;
    }
    p_sh = aC; ng_total_sh = aN;
  }
  __syncthreads();

  const unsigned sum_t = p_sh;                 // total positives (unmasked), exact
  const float p = (float)sum_t;
  const bool has_pos = sum_t > 0;
  const unsigned n_neg_total = (unsigned)PP - sum_t;
  int n_pos = (int)npos_shf;                   // tissue positives, exact
  int n_remain = KALL - n_pos; if (n_remain < 0) n_remain = 0;

  // ---- pass 2: descending walk (lovasz + OHEM top-k) ----
  float lov_local = 0.f, ns_local = 0.f;
  {
    unsigned I = sA[t], C = sB[t], NG = sC[t];
    float Jprev = has_pos ? (1.f - (p - (float)C) / (p + (float)I - (float)C)) : 0.f;
    #pragma unroll
    for (int k = 0; k < 4; ++k) {
      int j = NBINS - 1 - (t * CH + k);
      uint4 v = loc[k];
      unsigned c = v.x;
      if (c) {
        unsigned q = v.y;
        unsigned ng = (c - q) - v.z;
        float e = LOV_LO + ((float)j + 0.5f) * lov_d;
        if (has_pos) {
          float re = fmaxf(e, 0.f);
          if (n_neg_total > 0) {
            I += c; C += q;
            float Jb = 1.f - (p - (float)C) / (p + (float)I - (float)C);
            lov_local += re * (Jb - Jprev);
            Jprev = Jb;
          } else {
            double hi = (double)I + (double)c;
            double s = (hi * (hi + 1.0) - (double)I * ((double)I + 1.0)) * 0.5 / (double)p;
            lov_local += re * (float)s;
            I += c;
          }
        }
        if (n_remain > 0 && ng) {
          long long rem = (long long)n_remain - (long long)NG;
          unsigned take = rem <= 0 ? 0u : (rem >= (long long)ng ? ng : (unsigned)rem);
          if (take) {
            float l = e - 1.f;                         // negatives: e = 1 + l
            float nloss = fmaxf(l, 0.f) + __logf(1.f + __expf(-fabsf(l)));
            ns_local += (float)take * nloss;
          }
          NG += ng;
        }
      }
    }
  }
  sf[t] = lov_local; sg[t] = ns_local; __syncthreads();
  for (int off = 128; off > 0; off >>= 1) {
    if (t < off) { sf[t] += sf[t + off]; sg[t] += sg[t + off]; }
    __syncthreads();
  }

  if (t == 0) {
    float lov = sf[0];
    float neg_sum = sg[0];
    unsigned kept = (n_remain > 0)
        ? ((unsigned)n_remain < ng_total_sh ? (unsigned)n_remain : ng_total_sh) : 0u;
    float cnt = (float)n_pos + (float)kept;
    float ohem;
    if (cnt > 0.f) ohem = (pos_sh + neg_sum) / cnt;
    else ohem = ((float)PP - nm0_shf > 0.f) ? mx_sh : bce0g[b];
    float tp = tp_sh;
    float fn = p - tp;
    float fp = spr_sh - tp;
    float tv = (tp + 1e-6f) / (tp + 0.3f * fn + 0.7f * fp + 1e-6f);
    float ft = powf(fmaxf(1.f - tv, 0.f), 1.33f);
    acc[b].lov_i = lov; acc[b].ft_i = ft; acc[b].ohem_i = ohem;
    acc[b].posb = has_pos ? 1u : 0u;

    __threadfence();
    unsigned ret = atomicAdd(&tickets[0], 1u);
    if (ret == BB - 1) {                 // last image: final combine
      __threadfence();
      volatile AccR* va = acc;
      float os = 0.f, fts = 0.f, lvs = 0.f; int np = 0;
      for (int i = 0; i < BB; i++) {
        os += va[i].ohem_i;
        if (va[i].posb) { np++; fts += va[i].ft_i; lvs += va[i].lov_i; }
      }
      float denom = (np > 0) ? (float)np : 1.f;
      float r = os / (float)BB;
      if (np > 0) r += fts / denom + 0.2f * (lvs / denom);
      out[0] = r;
    }
  }
}

extern "C" void kernel_launch(void* const* d_in, const int* in_sizes, int n_in,
                              void* d_out, int out_size, void* d_ws, size_t ws_size,
                              hipStream_t stream) {
  const float* logits  = (const float*)d_in[0];
  const int*   targets = (const int*)d_in[1];
  const float* mask    = (const float*)d_in[2];
  float* out = (float*)d_out;

  char* ws = (char*)d_ws;
  AccR*     acc      = (AccR*)ws;                        // 256 B
  unsigned* tickets  = (unsigned*)(ws + 256);            // u32
  float*    bce0g    = (float*)(ws + 512);               // 64 B
  unsigned* flags    = (unsigned*)(ws + 4096);           // 16*144*4 = 9.2 KB
  uint4*    ghist    = (uint4*)(ws + (64 << 10));        // 16*1024*16 = 256 KB
  unsigned* partial1 = (unsigned*)(ws + (1 << 20));      // 16*144*1024*4 = 9.4 MB
  unsigned* partial3 = (unsigned*)(ws + (1 << 20) + (size_t)BB * CHUNKS * NBINS * 4);  // 9.4 MB
  (void)in_sizes; (void)n_in; (void)out_size; (void)ws_size;

  dim3 g1(CHUNKS, BB, 1);        // 2304 blocks, 8.3 KB LDS -> 6 blocks/CU (VGPR<=85)
  k_main<<<g1, 256, 0, stream>>>(logits, targets, mask, bce0g, partial1, partial3, flags);
  dim3 g2(NBINS / 64, BB, 1);    // 16 x 16 = 256 blocks
  k_reduce<<<g2, 256, 0, stream>>>(partial1, partial3, flags, ghist, tickets);
  k_scan<<<BB, 256, 0, stream>>>(ghist, bce0g, acc, tickets, out);
}